// Round 1
// baseline (23571.686 us; speedup 1.0000x reference)
//
#include <hip/hip_runtime.h>

#define S_LEN 4096
#define BATCH 16
#define HID   256     // H == F == 256
#define GATE4 1024    // 4F

typedef __bf16 bf16x8 __attribute__((ext_vector_type(8)));
typedef float  f32x4  __attribute__((ext_vector_type(4)));

union FragU {
    unsigned short u[8];
    bf16x8 v;
    uint4  q;
};

__device__ __forceinline__ unsigned short f2bf(float f) {
    unsigned u = __builtin_bit_cast(unsigned, f);
    u += 0x7fffu + ((u >> 16) & 1u);
    return (unsigned short)(u >> 16);
}
__device__ __forceinline__ float bf2f(unsigned short s) {
    unsigned u = ((unsigned)s) << 16;
    return __builtin_bit_cast(float, u);
}
__device__ __forceinline__ float sigmoid_f(float x) {
    return 1.f / (1.f + __expf(-x));
}
__device__ __forceinline__ float tanh_f(float x) {
    // 1 - 2/(e^{2x}+1): safe at +/-inf (no inf/inf)
    float e = __expf(2.f * x);
    return 1.f - 2.f / (e + 1.f);
}

// ---------------------------------------------------------------------------
// Kernel 0: zero the sequence flags (workspace is poisoned before each launch)
// ---------------------------------------------------------------------------
__global__ void init_seq(unsigned int* seq) {
    if (threadIdx.x < 128) seq[threadIdx.x] = 0u;
}

// ---------------------------------------------------------------------------
// Kernel 1: xp[d][s][b][j] = (sum_k x[b][t_eff][k] * Wi_d[k][j]) + bias_d[j]
// stored as bf16. M = S*B = 65536 (row r = t*16+b), K = 256, N = 1024 per dir.
// 64x64 tile, BK=32, 256 threads (4 waves, each a 32x32 region).
// ---------------------------------------------------------------------------
__global__ __launch_bounds__(256, 2) void xp_gemm(
    const float* __restrict__ X,       // inputs [B][S][H]
    const float* __restrict__ Wi_fw, const float* __restrict__ b_fw,
    const float* __restrict__ Wi_rv, const float* __restrict__ b_rv,
    unsigned short* __restrict__ xp_fw, unsigned short* __restrict__ xp_rv)
{
    const int dir = blockIdx.z;
    const float* Wi   = dir ? Wi_rv : Wi_fw;
    const float* bias = dir ? b_rv  : b_fw;
    unsigned short* xp = dir ? xp_rv : xp_fw;

    __shared__ unsigned short As[64][40];   // [m][k] bf16, padded pitch
    __shared__ unsigned short Bs[64][40];   // [n][k] bf16 (transposed), padded

    const int tid  = threadIdx.x;
    const int lane = tid & 63;
    const int wid  = tid >> 6;       // 0..3
    const int quad = lane >> 4;      // 0..3
    const int l16  = lane & 15;
    const int wm = wid >> 1, wn = wid & 1;

    const int r0 = blockIdx.x * 64;  // M block
    const int n0 = blockIdx.y * 64;  // N block within 1024

    // staging maps
    const int ai = tid & 63;             // A tile row
    const int ak = (tid >> 6) * 8;       // A k offset {0,8,16,24}
    const int bk = tid >> 3;             // B k row 0..31
    const int bj = (tid & 7) * 8;        // B n offset

    const int r  = r0 + ai;
    const int t  = r >> 4, bb = r & 15;
    const int t_eff = dir ? (S_LEN - 1 - t) : t;
    const float* Arow = X + ((size_t)bb * S_LEN + t_eff) * HID;

    f32x4 acc[2][2];
    #pragma unroll
    for (int i = 0; i < 2; ++i)
        #pragma unroll
        for (int j = 0; j < 2; ++j) { acc[i][j][0]=0.f; acc[i][j][1]=0.f; acc[i][j][2]=0.f; acc[i][j][3]=0.f; }

    for (int kb = 0; kb < HID / 32; ++kb) {
        // stage A (fp32 -> bf16)
        {
            const float* p = Arow + kb * 32 + ak;
            float4 v0 = *(const float4*)p;
            float4 v1 = *(const float4*)(p + 4);
            FragU fu;
            fu.u[0]=f2bf(v0.x); fu.u[1]=f2bf(v0.y); fu.u[2]=f2bf(v0.z); fu.u[3]=f2bf(v0.w);
            fu.u[4]=f2bf(v1.x); fu.u[5]=f2bf(v1.y); fu.u[6]=f2bf(v1.z); fu.u[7]=f2bf(v1.w);
            *(uint4*)&As[ai][ak] = fu.q;
        }
        // stage B transposed
        {
            const float* p = Wi + (size_t)(kb * 32 + bk) * GATE4 + n0 + bj;
            float4 v0 = *(const float4*)p;
            float4 v1 = *(const float4*)(p + 4);
            unsigned short tmp[8] = { f2bf(v0.x), f2bf(v0.y), f2bf(v0.z), f2bf(v0.w),
                                      f2bf(v1.x), f2bf(v1.y), f2bf(v1.z), f2bf(v1.w) };
            #pragma unroll
            for (int jj = 0; jj < 8; ++jj) Bs[bj + jj][bk] = tmp[jj];
        }
        __syncthreads();

        bf16x8 a0 = *(const bf16x8*)&As[wm * 32 + l16][quad * 8];
        bf16x8 a1 = *(const bf16x8*)&As[wm * 32 + 16 + l16][quad * 8];
        bf16x8 B0 = *(const bf16x8*)&Bs[wn * 32 + l16][quad * 8];
        bf16x8 B1 = *(const bf16x8*)&Bs[wn * 32 + 16 + l16][quad * 8];
        acc[0][0] = __builtin_amdgcn_mfma_f32_16x16x32_bf16(a0, B0, acc[0][0], 0, 0, 0);
        acc[0][1] = __builtin_amdgcn_mfma_f32_16x16x32_bf16(a0, B1, acc[0][1], 0, 0, 0);
        acc[1][0] = __builtin_amdgcn_mfma_f32_16x16x32_bf16(a1, B0, acc[1][0], 0, 0, 0);
        acc[1][1] = __builtin_amdgcn_mfma_f32_16x16x32_bf16(a1, B1, acc[1][1], 0, 0, 0);
        __syncthreads();
    }

    // epilogue: add bias, convert, store bf16
    #pragma unroll
    for (int am = 0; am < 2; ++am)
        #pragma unroll
        for (int bn = 0; bn < 2; ++bn) {
            int ncol = n0 + wn * 32 + bn * 16 + l16;
            float bv = bias[ncol];
            #pragma unroll
            for (int rr = 0; rr < 4; ++rr) {
                int rrow = r0 + wm * 32 + am * 16 + quad * 4 + rr;
                float v = acc[am][bn][rr] + bv;
                xp[(size_t)rrow * GATE4 + ncol] = f2bf(v);
            }
        }
}

// ---------------------------------------------------------------------------
// Kernel 2: the recurrence. 4 WGs: (dir, half). WG owns f in
// [half*128, half*128+128) for all 4 gates; Wh columns for those gates live
// entirely in VGPRs as MFMA B-fragments. Per-step pairwise exchange of the
// 16x128 bf16 h-half through global memory + agent-scope flags.
// ---------------------------------------------------------------------------
__global__ __launch_bounds__(512, 2) void lstm_rec(
    const float* __restrict__ Wh_fw, const float* __restrict__ Wh_rv,
    const unsigned short* __restrict__ xp_fw, const unsigned short* __restrict__ xp_rv,
    float* __restrict__ out,            // [B][S][512]
    float* __restrict__ finals,         // c_fw,h_fw,c_rv,h_rv (each 16x256)
    unsigned short* __restrict__ exch,  // [dir][parity][half][16][128] bf16
    unsigned int* __restrict__ seq)     // flag per (dir,half), stride 32 uints
{
    const int wgid = blockIdx.x;        // 0..3
    const int dir  = wgid >> 1;
    const int half = wgid & 1;
    const float* Wh = dir ? Wh_rv : Wh_fw;
    const unsigned short* xp = dir ? xp_rv : xp_fw;

    const int tid  = threadIdx.x;
    const int lane = tid & 63;
    const int wid  = tid >> 6;          // 0..7
    const int quad = lane >> 4;
    const int l16  = lane & 15;

    const int fbase = half * 128 + wid * 16;   // dir-local f of this wave's block

    __shared__ unsigned short hbuf[16][264];   // full h (bf16), padded pitch

    // h0 = 0
    for (int i = tid; i < 16 * 264; i += 512) ((unsigned short*)hbuf)[i] = 0;

    // Load Wh into B-fragments (one-time): Bfrag[g][kt], lane holds
    // Wh[k = kt*32 + quad*8 + j][g*256 + fbase + l16], j=0..7.
    bf16x8 Bfrag[4][8];
    #pragma unroll
    for (int g = 0; g < 4; ++g) {
        int col = g * 256 + fbase + l16;
        #pragma unroll
        for (int kt = 0; kt < 8; ++kt) {
            FragU fu;
            #pragma unroll
            for (int j = 0; j < 8; ++j) {
                int k = kt * 32 + quad * 8 + j;
                fu.u[j] = f2bf(Wh[(size_t)k * GATE4 + col]);
            }
            Bfrag[g][kt] = fu.v;
        }
    }

    float cst[4]  = {0.f, 0.f, 0.f, 0.f};
    float hval[4] = {0.f, 0.f, 0.f, 0.f};
    __syncthreads();

    unsigned int* myseq = seq + (dir * 2 + half) * 32;
    unsigned int* pseq  = seq + (dir * 2 + (1 - half)) * 32;

    for (int s = 0; s < S_LEN; ++s) {
        const int parity = s & 1;
        const bool last = (s == S_LEN - 1);

        // xp loads for this step (issued early, consumed after MFMA)
        float xpz[4][4];
        {
            const unsigned short* xprow = xp + (size_t)s * BATCH * GATE4;
            #pragma unroll
            for (int g = 0; g < 4; ++g)
                #pragma unroll
                for (int rr = 0; rr < 4; ++rr) {
                    int m = quad * 4 + rr;
                    xpz[g][rr] = bf2f(xprow[m * GATE4 + g * 256 + fbase + l16]);
                }
        }

        // A-fragments from h in LDS: A[m=l16][k = kt*32 + quad*8 + j]
        bf16x8 Afrag[8];
        #pragma unroll
        for (int kt = 0; kt < 8; ++kt)
            Afrag[kt] = *(const bf16x8*)&hbuf[l16][kt * 32 + quad * 8];
        __syncthreads();   // everyone done reading h before it is overwritten

        f32x4 accg[4];
        #pragma unroll
        for (int g = 0; g < 4; ++g) { accg[g][0]=0.f; accg[g][1]=0.f; accg[g][2]=0.f; accg[g][3]=0.f; }
        #pragma unroll
        for (int kt = 0; kt < 8; ++kt) {
            accg[0] = __builtin_amdgcn_mfma_f32_16x16x32_bf16(Afrag[kt], Bfrag[0][kt], accg[0], 0, 0, 0);
            accg[1] = __builtin_amdgcn_mfma_f32_16x16x32_bf16(Afrag[kt], Bfrag[1][kt], accg[1], 0, 0, 0);
            accg[2] = __builtin_amdgcn_mfma_f32_16x16x32_bf16(Afrag[kt], Bfrag[2][kt], accg[2], 0, 0, 0);
            accg[3] = __builtin_amdgcn_mfma_f32_16x16x32_bf16(Afrag[kt], Bfrag[3][kt], accg[3], 0, 0, 0);
        }

        // gates (all in registers): lane owns (m = quad*4+rr, f = fbase+l16)
        unsigned short hb[4];
        #pragma unroll
        for (int rr = 0; rr < 4; ++rr) {
            float zi = accg[0][rr] + xpz[0][rr];
            float zf = accg[1][rr] + xpz[1][rr];
            float zg = accg[2][rr] + xpz[2][rr];
            float zo = accg[3][rr] + xpz[3][rr];
            float ig = sigmoid_f(zi);
            float fg = sigmoid_f(zf);
            float gg = tanh_f(zg);
            float og = sigmoid_f(zo);
            float c  = fg * cst[rr] + ig * gg;
            cst[rr]  = c;
            hval[rr] = og * tanh_f(c);
            hb[rr]   = f2bf(hval[rr]);
        }

        // own half -> LDS
        #pragma unroll
        for (int rr = 0; rr < 4; ++rr) {
            int m = quad * 4 + rr;
            hbuf[m][fbase + l16] = hb[rr];
        }

        if (!last) {
            // publish own half for partner (double-buffered by parity)
            unsigned short* ex = exch + (size_t)(((dir * 2 + parity) * 2) + half) * (16 * 128);
            #pragma unroll
            for (int rr = 0; rr < 4; ++rr) {
                int m = quad * 4 + rr;
                int floc = wid * 16 + l16;
                ex[m * 128 + floc] = hb[rr];
            }
            __threadfence();       // each thread drains its own stores to L2
            __syncthreads();       // all threads' fences complete
            if (tid == 0)
                __hip_atomic_store(myseq, (unsigned)(s + 1), __ATOMIC_RELEASE, __HIP_MEMORY_SCOPE_AGENT);
        }

        // fp32 output write (after flag so partner gets a head start)
        {
            int t_orig = dir ? (S_LEN - 1 - s) : s;
            #pragma unroll
            for (int rr = 0; rr < 4; ++rr) {
                int m = quad * 4 + rr;
                out[((size_t)m * S_LEN + t_orig) * 512 + dir * 256 + fbase + l16] = hval[rr];
            }
        }

        if (last) break;

        // wait for partner's half of this step
        if (tid == 0) {
            while (__hip_atomic_load(pseq, __ATOMIC_ACQUIRE, __HIP_MEMORY_SCOPE_AGENT) < (unsigned)(s + 1)) {
                __builtin_amdgcn_s_sleep(1);
            }
        }
        __syncthreads();

        // partner half -> LDS (agent-scope dword loads: bypass stale caches)
        {
            const unsigned int* exw = (const unsigned int*)(exch +
                (size_t)(((dir * 2 + parity) * 2) + (1 - half)) * (16 * 128));
            int po = (1 - half) * 128;
            for (int i = tid; i < 16 * 64; i += 512) {
                int m = i >> 6, fp = i & 63;
                unsigned int v = __hip_atomic_load(&exw[i], __ATOMIC_RELAXED, __HIP_MEMORY_SCOPE_AGENT);
                *(unsigned int*)&hbuf[m][po + fp * 2] = v;
            }
        }
        __syncthreads();
    }

    // final states: c then h, fw block then rv block
    {
        float* cdst = finals + (dir ? 8192 : 0);
        float* hdst = cdst + 4096;
        #pragma unroll
        for (int rr = 0; rr < 4; ++rr) {
            int m = quad * 4 + rr;
            int f = fbase + l16;
            cdst[m * 256 + f] = cst[rr];
            hdst[m * 256 + f] = hval[rr];
        }
    }
}

// ---------------------------------------------------------------------------
extern "C" void kernel_launch(void* const* d_in, const int* in_sizes, int n_in,
                              void* d_out, int out_size, void* d_ws, size_t ws_size,
                              hipStream_t stream)
{
    const float* X     = (const float*)d_in[0];
    const float* Wi_fw = (const float*)d_in[1];
    const float* Wh_fw = (const float*)d_in[2];
    const float* b_fw  = (const float*)d_in[3];
    const float* Wi_rv = (const float*)d_in[4];
    const float* Wh_rv = (const float*)d_in[5];
    const float* b_rv  = (const float*)d_in[6];

    float* out    = (float*)d_out;
    float* finals = out + (size_t)BATCH * S_LEN * 512;

    char* ws = (char*)d_ws;
    unsigned short* xp_fw = (unsigned short*)ws;                          // 128 MiB
    unsigned short* xp_rv = (unsigned short*)(ws + 134217728ull);         // 128 MiB
    unsigned short* exch  = (unsigned short*)(ws + 268435456ull);         // 32 KiB
    unsigned int*   seq   = (unsigned int*)(ws + 268435456ull + 32768ull);// 512 B

    init_seq<<<1, 128, 0, stream>>>(seq);

    dim3 g(65536 / 64, 1024 / 64, 2);
    xp_gemm<<<g, 256, 0, stream>>>(X, Wi_fw, b_fw, Wi_rv, b_rv, xp_fw, xp_rv);

    lstm_rec<<<4, 512, 0, stream>>>(Wh_fw, Wh_rv, xp_fw, xp_rv, out, finals, exch, seq);
}